// Round 11
// baseline (113.562 us; speedup 1.0000x reference)
//
#include <hip/hip_runtime.h>
#include <hip/hip_bf16.h>

#define NHEAD 12
#define HSZ   64
#define BATCH 8
#define SEQ   1024
#define KDIM  768
#define NDIM  1536   // NHEAD * HSZ * 2

using f32x4  = __attribute__((ext_vector_type(4))) float;
using bf16x8 = __attribute__((ext_vector_type(8))) __bf16;
typedef unsigned int u32;

__device__ __forceinline__ unsigned short f2bf(float f) {
    unsigned int u = __builtin_bit_cast(unsigned int, f);
    u += 0x7fffu + ((u >> 16) & 1u);   // RNE
    return (unsigned short)(u >> 16);
}

// async global->LDS, 16B per lane; LDS dest = wave-uniform base + lane*16
__device__ __forceinline__ void gl_lds16(const unsigned short* g, unsigned short* l) {
    __builtin_amdgcn_global_load_lds(
        (const __attribute__((address_space(1))) u32*)g,
        (__attribute__((address_space(3))) u32*)l, 16, 0, 0);
}

// byte-block swizzle within a 128B LDS row: 16B block j of row r lives at j^(r&7)
__device__ __forceinline__ int swz16(int row, int c16) { return (c16 ^ (row & 7)); }

// ---------------------------------------------------------------------------
// prep: (a) input fp32 -> bf16   (b) W -> Wt bf16 transpose   (c) sin/cos table
// ---------------------------------------------------------------------------
#define NCONV 3072          // (8192*768)/(256*8)
#define NTRAN 1152          // 48 * 24 tiles of 32x32
#define NTAB  128           // 32768 / 256
__global__ __launch_bounds__(256) void prep(
        const float* __restrict__ input, const float* __restrict__ W,
        unsigned short* __restrict__ Abf, unsigned short* __restrict__ Wt,
        float2* __restrict__ tab) {
    __shared__ unsigned short tl[32][33];
    const int b = blockIdx.x, t = threadIdx.x;
    if (b < NCONV) {
        const size_t base = ((size_t)b * 256 + t) * 8;
        const f32x4 v0 = *reinterpret_cast<const f32x4*>(input + base);
        const f32x4 v1 = *reinterpret_cast<const f32x4*>(input + base + 4);
        uint4 o;
        o.x = (u32)f2bf(v0[0]) | ((u32)f2bf(v0[1]) << 16);
        o.y = (u32)f2bf(v0[2]) | ((u32)f2bf(v0[3]) << 16);
        o.z = (u32)f2bf(v1[0]) | ((u32)f2bf(v1[1]) << 16);
        o.w = (u32)f2bf(v1[2]) | ((u32)f2bf(v1[3]) << 16);
        *reinterpret_cast<uint4*>(Abf + base) = o;
    } else if (b < NCONV + NTRAN) {
        const int tb = b - NCONV;
        const int n0 = (tb % 48) * 32, k0 = (tb / 48) * 32;
        const int tx = t & 31, ty = t >> 5;   // 32 x 8
#pragma unroll
        for (int r = 0; r < 4; ++r)
            tl[ty + r * 8][tx] = f2bf(W[(size_t)(k0 + ty + r * 8) * NDIM + n0 + tx]);
        __syncthreads();
#pragma unroll
        for (int r = 0; r < 4; ++r)
            Wt[(size_t)(n0 + ty + r * 8) * KDIM + k0 + tx] = tl[tx][ty + r * 8];
    } else {
        const int idx = (b - NCONV - NTRAN) * 256 + t;   // < 32768
        const int s = idx >> 5, i = idx & 31;
        const float inv = exp2f(-(float)i * (13.287712379549449f / 32.0f));
        const float ang = (float)s * inv;
        tab[idx] = make_float2(sinf(ang), cosf(ang));
    }
}

// ---------------------------------------------------------------------------
// GEMM1: hidden = input @ W + b, RoPE, Q(prescaled)/K bf16.
// 128x128 tile, 512 thr / 8 waves (2m x 4n), wave-tile 64x32.
// NEW: BK=32 double-buffered 2-phase prefetch -- STAGE(next) issued BEFORE
// compute(cur), one barrier per step; LDS stays 32 KB (occupancy unchanged).
// Same r2-form epilogue; XCD-chunked grid (768 = 8 x 96).
// ---------------------------------------------------------------------------
__global__ __launch_bounds__(512, 6) void gemm1_rope(
        const unsigned short* __restrict__ Abf, const unsigned short* __restrict__ Wt,
        const float* __restrict__ bias, const float2* __restrict__ tab,
        unsigned short* __restrict__ qws, unsigned short* __restrict__ kws) {
    __shared__ unsigned short As[2][128 * 32];   // 8 KB each, swizzled 16B blocks
    __shared__ unsigned short Bs[2][128 * 32];
    const int t  = threadIdx.x;
    const int flat = blockIdx.x;
    const int id = (flat & 7) * 96 + (flat >> 3);   // bijective: 768 = 8*96
    const int mt = id / 12, nt = id % 12;
    const int m0 = mt * 128, n0 = nt * 128;
    const int lane = t & 63, wid = t >> 6;          // wid 0..7
    const int wm = wid >> 2, wn = wid & 3;          // 2 x 4 wave grid
    const int lr = lane & 15, lg = lane >> 4;
    // staging map (BK=32, 64B rows of 4 x 16B blocks): lane l -> row wid*16+(l>>2),
    // linear block (l&3); source block pre-swizzled: (l&3)^((l>>2)&3)
    const int srow = wid * 16 + (lane >> 2);
    const int soff = (((lane & 3) ^ ((lane >> 2) & 3)) * 8);

    f32x4 acc[4][2] = {};

    // prologue: stage k-tile 0 into buffer 0
    gl_lds16(Abf + (size_t)(m0 + srow) * KDIM + soff, &As[0][wid * 16 * 32]);
    gl_lds16(Wt  + (size_t)(n0 + srow) * KDIM + soff, &Bs[0][wid * 16 * 32]);
    __syncthreads();

    for (int kt = 0; kt < KDIM / 32; ++kt) {
        const int cur = kt & 1;
        if (kt < KDIM / 32 - 1) {   // issue next-tile loads FIRST (hide under compute)
            const int kbase = (kt + 1) * 32;
            gl_lds16(Abf + (size_t)(m0 + srow) * KDIM + kbase + soff, &As[cur ^ 1][wid * 16 * 32]);
            gl_lds16(Wt  + (size_t)(n0 + srow) * KDIM + kbase + soff, &Bs[cur ^ 1][wid * 16 * 32]);
        }
        const char* ac = reinterpret_cast<const char*>(&As[cur][0]);
        const char* bc = reinterpret_cast<const char*>(&Bs[cur][0]);
        bf16x8 a[4], b[2];
#pragma unroll
        for (int mf = 0; mf < 4; ++mf) {
            const int r = wm * 64 + mf * 16 + lr;
            a[mf] = *reinterpret_cast<const bf16x8*>(ac + r * 64 + ((lg ^ (r & 3)) * 16));
        }
#pragma unroll
        for (int nf = 0; nf < 2; ++nf) {
            const int r = wn * 32 + nf * 16 + lr;
            b[nf] = *reinterpret_cast<const bf16x8*>(bc + r * 64 + ((lg ^ (r & 3)) * 16));
        }
#pragma unroll
        for (int mf = 0; mf < 4; ++mf)
#pragma unroll
            for (int nf = 0; nf < 2; ++nf)
                acc[mf][nf] = __builtin_amdgcn_mfma_f32_16x16x32_bf16(
                    a[mf], b[nf], acc[mf][nf], 0, 0, 0);
        __syncthreads();   // drains staged loads; all waves done reading cur
    }

    float bv[2];
#pragma unroll
    for (int nf = 0; nf < 2; ++nf) bv[nf] = bias[n0 + wn * 32 + nf * 16 + lr];
    const int h = nt;
    unsigned short* outw = (wn < 2) ? qws : kws;
    const float oscale = (wn < 2) ? 0.28867513459481287f : 1.0f;   // 1/sqrt(12)
#pragma unroll
    for (int nf = 0; nf < 2; ++nf) {
        const int d = (wn * 32 + nf * 16 + lr) & 63;   // channel within q or k
        const int i = d >> 1;
        const float sgn = (d & 1) ? 1.0f : -1.0f;
#pragma unroll
        for (int mf = 0; mf < 4; ++mf) {
#pragma unroll
            for (int r = 0; r < 4; ++r) {
                const int m = m0 + wm * 64 + mf * 16 + lg * 4 + r;
                const float v = acc[mf][nf][r] + bv[nf];
                const float p = __shfl_xor(v, 1, 64);   // pair partner (col n^1)
                const int s = m & (SEQ - 1), b_ = m >> 10;
                const float2 sc = tab[s * 32 + i];
                const float o = (v * sc.y + sgn * p * sc.x) * oscale;
                outw[(size_t)(((b_ * NHEAD + h) * SEQ + s) * HSZ) + d] = f2bf(o);
            }
        }
    }
}

// ---------------------------------------------------------------------------
// GEMM2 (r6 verbatim): logits[bh][m][n] = Q[bh] . K[bh]^T  (scale in Q)
// Full-cacheline LDS-staged NT stores; XCD-chunked block swizzle.
// ---------------------------------------------------------------------------
__global__ __launch_bounds__(256) void qk_logits(
        const unsigned short* __restrict__ qws, const unsigned short* __restrict__ kws,
        float* __restrict__ out) {
    __shared__ __align__(16) char smem[32768];
    unsigned short* Qs = reinterpret_cast<unsigned short*>(smem);            // 16 KB
    unsigned short* Ks = reinterpret_cast<unsigned short*>(smem + 16384);    // 16 KB
    const int t = threadIdx.x;
    // bijective XCD swizzle: 6144 blocks, 768 per XCD -> 12 contiguous bh per XCD
    const int flat = blockIdx.x;
    const int id = (flat & 7) * 768 + (flat >> 3);
    const int bh = id >> 6, tile = id & 63;
    const int tm = tile >> 3, tn = tile & 7;
    const int m0 = tm * 128, n0 = tn * 128;
    const unsigned short* Qb = qws + (size_t)bh * SEQ * HSZ;
    const unsigned short* Kb = kws + (size_t)bh * SEQ * HSZ;
    const int lane = t & 63, wid = t >> 6;
    const int lr8 = lane >> 3;
    const int src8 = ((lane & 7) ^ lr8) * 8;
#pragma unroll
    for (int p = 0; p < 4; ++p) {
        const int rb = wid * 32 + p * 8;
        gl_lds16(Qb + (size_t)(m0 + rb + lr8) * HSZ + src8, Qs + rb * 64);
        gl_lds16(Kb + (size_t)(n0 + rb + lr8) * HSZ + src8, Ks + rb * 64);
    }
    __syncthreads();
    const int wm = wid >> 1, wn = wid & 1;
    const int lr = lane & 15, lg = lane >> 4;
    char* qsb = smem;
    char* ksb = smem + 16384;
    f32x4 acc[4][4] = {};
#pragma unroll
    for (int kk = 0; kk < 2; ++kk) {
        bf16x8 a[4], b[4];
#pragma unroll
        for (int mf = 0; mf < 4; ++mf) {
            const int r = wm * 64 + mf * 16 + lr;
            a[mf] = *reinterpret_cast<const bf16x8*>(qsb + r * 128 + swz16(r, kk * 4 + lg) * 16);
        }
#pragma unroll
        for (int nf = 0; nf < 4; ++nf) {
            const int r = wn * 64 + nf * 16 + lr;
            b[nf] = *reinterpret_cast<const bf16x8*>(ksb + r * 128 + swz16(r, kk * 4 + lg) * 16);
        }
#pragma unroll
        for (int mf = 0; mf < 4; ++mf)
#pragma unroll
            for (int nf = 0; nf < 4; ++nf)
                acc[mf][nf] = __builtin_amdgcn_mfma_f32_16x16x32_bf16(
                    a[mf], b[nf], acc[mf][nf], 0, 0, 0);
    }
    float* ob = out + (size_t)bh * SEQ * SEQ;
    // chunk c: m-rows [c*64, c*64+64), 64 x 128 fp32 = 32 KB in LDS
#pragma unroll
    for (int c = 0; c < 2; ++c) {
        __syncthreads();
        if (wm == c) {
#pragma unroll
            for (int mf = 0; mf < 4; ++mf) {
#pragma unroll
                for (int nf = 0; nf < 4; ++nf) {
                    const int nc = wn * 64 + nf * 16 + lr;       // 0..127
                    const int b16 = nc >> 2;                     // 0..31
#pragma unroll
                    for (int r = 0; r < 4; ++r) {
                        const int ml = mf * 16 + lg * 4 + r;     // 0..63
                        const int sb = (b16 & 24) | ((b16 & 7) ^ (ml & 7));
                        *reinterpret_cast<float*>(smem + ml * 512 + sb * 16 + (nc & 3) * 4)
                            = acc[mf][nf][r];
                    }
                }
            }
        }
        __syncthreads();
#pragma unroll
        for (int it = 0; it < 8; ++it) {
            const int fl = it * 256 + t;       // 0..2047 float4 index
            const int ml = fl >> 5;            // 0..63
            const int b = fl & 31;             // logical 16B block
            const int sb = (b & 24) | ((b & 7) ^ (ml & 7));
            const f32x4 v = *reinterpret_cast<const f32x4*>(smem + ml * 512 + sb * 16);
            __builtin_nontemporal_store(v,
                reinterpret_cast<f32x4*>(ob + (size_t)(m0 + c * 64 + ml) * SEQ + n0 + b * 4));
        }
    }
}

extern "C" void kernel_launch(void* const* d_in, const int* in_sizes, int n_in,
                              void* d_out, int out_size, void* d_ws, size_t ws_size,
                              hipStream_t stream) {
    const float* input = (const float*)d_in[0];
    const float* W     = (const float*)d_in[1];
    const float* bias  = (const float*)d_in[2];
    float* out = (float*)d_out;

    const size_t QK_ELEMS = (size_t)BATCH * NHEAD * SEQ * HSZ;   // 6.29M
    unsigned short* qws = (unsigned short*)d_ws;
    unsigned short* kws = qws + QK_ELEMS;
    unsigned short* Wt  = kws + QK_ELEMS;
    unsigned short* Abf = Wt + (size_t)NDIM * KDIM;
    float2* tab = (float2*)(Abf + (size_t)BATCH * SEQ * KDIM);

    hipLaunchKernelGGL(prep, dim3(NCONV + NTRAN + NTAB), dim3(256), 0, stream,
                       input, W, Abf, Wt, tab);
    hipLaunchKernelGGL(gemm1_rope, dim3(768), dim3(512), 0, stream,
                       Abf, Wt, bias, tab, qws, kws);
    hipLaunchKernelGGL(qk_logits, dim3(96 * 64), dim3(256), 0, stream, qws, kws, out);
}

// Round 12
// 108.680 us; speedup vs baseline: 1.0449x; 1.0449x over previous
//
#include <hip/hip_runtime.h>
#include <hip/hip_bf16.h>

#define NHEAD 12
#define HSZ   64
#define BATCH 8
#define SEQ   1024
#define KDIM  768
#define NDIM  1536   // NHEAD * HSZ * 2

using f32x4  = __attribute__((ext_vector_type(4))) float;
using bf16x8 = __attribute__((ext_vector_type(8))) __bf16;
typedef unsigned int u32;

__device__ __forceinline__ unsigned short f2bf(float f) {
    unsigned int u = __builtin_bit_cast(unsigned int, f);
    u += 0x7fffu + ((u >> 16) & 1u);   // RNE
    return (unsigned short)(u >> 16);
}

// async global->LDS, 16B per lane; LDS dest = wave-uniform base + lane*16
__device__ __forceinline__ void gl_lds16(const unsigned short* g, unsigned short* l) {
    __builtin_amdgcn_global_load_lds(
        (const __attribute__((address_space(1))) u32*)g,
        (__attribute__((address_space(3))) u32*)l, 16, 0, 0);
}

// byte-block swizzle within a 128B LDS row: 16B block j of row r lives at j^(r&7)
__device__ __forceinline__ int swz16(int row, int c16) { return (c16 ^ (row & 7)); }

// ---------------------------------------------------------------------------
// prep: (a) input fp32 -> bf16   (b) W -> Wt bf16 transpose   (c) sin/cos table
// ---------------------------------------------------------------------------
#define NCONV 3072          // (8192*768)/(256*8)
#define NTRAN 1152          // 48 * 24 tiles of 32x32
#define NTAB  128           // 32768 / 256
__global__ __launch_bounds__(256) void prep(
        const float* __restrict__ input, const float* __restrict__ W,
        unsigned short* __restrict__ Abf, unsigned short* __restrict__ Wt,
        float2* __restrict__ tab) {
    __shared__ unsigned short tl[32][33];
    const int b = blockIdx.x, t = threadIdx.x;
    if (b < NCONV) {
        const size_t base = ((size_t)b * 256 + t) * 8;
        const f32x4 v0 = *reinterpret_cast<const f32x4*>(input + base);
        const f32x4 v1 = *reinterpret_cast<const f32x4*>(input + base + 4);
        uint4 o;
        o.x = (u32)f2bf(v0[0]) | ((u32)f2bf(v0[1]) << 16);
        o.y = (u32)f2bf(v0[2]) | ((u32)f2bf(v0[3]) << 16);
        o.z = (u32)f2bf(v1[0]) | ((u32)f2bf(v1[1]) << 16);
        o.w = (u32)f2bf(v1[2]) | ((u32)f2bf(v1[3]) << 16);
        *reinterpret_cast<uint4*>(Abf + base) = o;
    } else if (b < NCONV + NTRAN) {
        const int tb = b - NCONV;
        const int n0 = (tb % 48) * 32, k0 = (tb / 48) * 32;
        const int tx = t & 31, ty = t >> 5;   // 32 x 8
#pragma unroll
        for (int r = 0; r < 4; ++r)
            tl[ty + r * 8][tx] = f2bf(W[(size_t)(k0 + ty + r * 8) * NDIM + n0 + tx]);
        __syncthreads();
#pragma unroll
        for (int r = 0; r < 4; ++r)
            Wt[(size_t)(n0 + ty + r * 8) * KDIM + k0 + tx] = tl[tx][ty + r * 8];
    } else {
        const int idx = (b - NCONV - NTRAN) * 256 + t;   // < 32768
        const int s = idx >> 5, i = idx & 31;
        const float inv = exp2f(-(float)i * (13.287712379549449f / 32.0f));
        const float ang = (float)s * inv;
        tab[idx] = make_float2(sinf(ang), cosf(ang));
    }
}

// ---------------------------------------------------------------------------
// GEMM1 (r10 verbatim): hidden = input @ W + b, RoPE, Q(prescaled)/K bf16.
// Tile 128x128, BK=64, 512 threads / 8 waves (2m x 4n), wave-tile 64x32.
// launch_bounds(512,6) -> ~3 blocks/CU = 24 waves/CU. 2-barrier K-loop,
// r2-form epilogue, XCD-chunked grid (768 = 8 x 96).
// ---------------------------------------------------------------------------
__global__ __launch_bounds__(512, 6) void gemm1_rope(
        const unsigned short* __restrict__ Abf, const unsigned short* __restrict__ Wt,
        const float* __restrict__ bias, const float2* __restrict__ tab,
        unsigned short* __restrict__ qws, unsigned short* __restrict__ kws) {
    __shared__ unsigned short As[128 * 64];   // [m][k] bf16, swizzled 16B blocks
    __shared__ unsigned short Bs[128 * 64];   // [n][k] bf16, swizzled
    const int t  = threadIdx.x;
    const int flat = blockIdx.x;
    const int id = (flat & 7) * 96 + (flat >> 3);   // bijective: 768 = 8*96
    const int mt = id / 12, nt = id % 12;
    const int m0 = mt * 128, n0 = nt * 128;
    const int lane = t & 63, wid = t >> 6;          // wid 0..7
    const int wm = wid >> 2, wn = wid & 3;          // 2 x 4 wave grid
    const int lr = lane & 15, lg = lane >> 4;
    const int lr8 = lane >> 3;
    const int src8 = ((lane & 7) ^ lr8) * 8;

    f32x4 acc[4][2] = {};
    char* asb = reinterpret_cast<char*>(As);
    char* bsb = reinterpret_cast<char*>(Bs);

    for (int kt = 0; kt < KDIM / 64; ++kt) {
        if (kt) __syncthreads();
        const int kbase = kt * 64;
#pragma unroll
        for (int p = 0; p < 2; ++p) {
            const int rb = wid * 16 + p * 8;       // 8 waves x 16 rows
            gl_lds16(Abf + (size_t)(m0 + rb + lr8) * KDIM + kbase + src8, As + rb * 64);
            gl_lds16(Wt  + (size_t)(n0 + rb + lr8) * KDIM + kbase + src8, Bs + rb * 64);
        }
        __syncthreads();
#pragma unroll
        for (int kk = 0; kk < 2; ++kk) {
            bf16x8 a[4], b[2];
#pragma unroll
            for (int mf = 0; mf < 4; ++mf) {
                const int r = wm * 64 + mf * 16 + lr;
                a[mf] = *reinterpret_cast<const bf16x8*>(asb + r * 128 + swz16(r, kk * 4 + lg) * 16);
            }
#pragma unroll
            for (int nf = 0; nf < 2; ++nf) {
                const int r = wn * 32 + nf * 16 + lr;
                b[nf] = *reinterpret_cast<const bf16x8*>(bsb + r * 128 + swz16(r, kk * 4 + lg) * 16);
            }
#pragma unroll
            for (int mf = 0; mf < 4; ++mf)
#pragma unroll
                for (int nf = 0; nf < 2; ++nf)
                    acc[mf][nf] = __builtin_amdgcn_mfma_f32_16x16x32_bf16(
                        a[mf], b[nf], acc[mf][nf], 0, 0, 0);
        }
    }

    float bv[2];
#pragma unroll
    for (int nf = 0; nf < 2; ++nf) bv[nf] = bias[n0 + wn * 32 + nf * 16 + lr];
    const int h = nt;
    unsigned short* outw = (wn < 2) ? qws : kws;
    const float oscale = (wn < 2) ? 0.28867513459481287f : 1.0f;   // 1/sqrt(12)
#pragma unroll
    for (int nf = 0; nf < 2; ++nf) {
        const int d = (wn * 32 + nf * 16 + lr) & 63;   // channel within q or k
        const int i = d >> 1;
        const float sgn = (d & 1) ? 1.0f : -1.0f;
#pragma unroll
        for (int mf = 0; mf < 4; ++mf) {
#pragma unroll
            for (int r = 0; r < 4; ++r) {
                const int m = m0 + wm * 64 + mf * 16 + lg * 4 + r;
                const float v = acc[mf][nf][r] + bv[nf];
                const float p = __shfl_xor(v, 1, 64);   // pair partner (col n^1)
                const int s = m & (SEQ - 1), b_ = m >> 10;
                const float2 sc = tab[s * 32 + i];
                const float o = (v * sc.y + sgn * p * sc.x) * oscale;
                outw[(size_t)(((b_ * NHEAD + h) * SEQ + s) * HSZ) + d] = f2bf(o);
            }
        }
    }
}

// ---------------------------------------------------------------------------
// GEMM2 (r6 verbatim): logits[bh][m][n] = Q[bh] . K[bh]^T  (scale in Q)
// Full-cacheline LDS-staged NT stores; XCD-chunked block swizzle.
// ---------------------------------------------------------------------------
__global__ __launch_bounds__(256) void qk_logits(
        const unsigned short* __restrict__ qws, const unsigned short* __restrict__ kws,
        float* __restrict__ out) {
    __shared__ __align__(16) char smem[32768];
    unsigned short* Qs = reinterpret_cast<unsigned short*>(smem);            // 16 KB
    unsigned short* Ks = reinterpret_cast<unsigned short*>(smem + 16384);    // 16 KB
    const int t = threadIdx.x;
    // bijective XCD swizzle: 6144 blocks, 768 per XCD -> 12 contiguous bh per XCD
    const int flat = blockIdx.x;
    const int id = (flat & 7) * 768 + (flat >> 3);
    const int bh = id >> 6, tile = id & 63;
    const int tm = tile >> 3, tn = tile & 7;
    const int m0 = tm * 128, n0 = tn * 128;
    const unsigned short* Qb = qws + (size_t)bh * SEQ * HSZ;
    const unsigned short* Kb = kws + (size_t)bh * SEQ * HSZ;
    const int lane = t & 63, wid = t >> 6;
    const int lr8 = lane >> 3;
    const int src8 = ((lane & 7) ^ lr8) * 8;
#pragma unroll
    for (int p = 0; p < 4; ++p) {
        const int rb = wid * 32 + p * 8;
        gl_lds16(Qb + (size_t)(m0 + rb + lr8) * HSZ + src8, Qs + rb * 64);
        gl_lds16(Kb + (size_t)(n0 + rb + lr8) * HSZ + src8, Ks + rb * 64);
    }
    __syncthreads();
    const int wm = wid >> 1, wn = wid & 1;
    const int lr = lane & 15, lg = lane >> 4;
    char* qsb = smem;
    char* ksb = smem + 16384;
    f32x4 acc[4][4] = {};
#pragma unroll
    for (int kk = 0; kk < 2; ++kk) {
        bf16x8 a[4], b[4];
#pragma unroll
        for (int mf = 0; mf < 4; ++mf) {
            const int r = wm * 64 + mf * 16 + lr;
            a[mf] = *reinterpret_cast<const bf16x8*>(qsb + r * 128 + swz16(r, kk * 4 + lg) * 16);
        }
#pragma unroll
        for (int nf = 0; nf < 4; ++nf) {
            const int r = wn * 64 + nf * 16 + lr;
            b[nf] = *reinterpret_cast<const bf16x8*>(ksb + r * 128 + swz16(r, kk * 4 + lg) * 16);
        }
#pragma unroll
        for (int mf = 0; mf < 4; ++mf)
#pragma unroll
            for (int nf = 0; nf < 4; ++nf)
                acc[mf][nf] = __builtin_amdgcn_mfma_f32_16x16x32_bf16(
                    a[mf], b[nf], acc[mf][nf], 0, 0, 0);
    }
    float* ob = out + (size_t)bh * SEQ * SEQ;
    // chunk c: m-rows [c*64, c*64+64), 64 x 128 fp32 = 32 KB in LDS
#pragma unroll
    for (int c = 0; c < 2; ++c) {
        __syncthreads();
        if (wm == c) {
#pragma unroll
            for (int mf = 0; mf < 4; ++mf) {
#pragma unroll
                for (int nf = 0; nf < 4; ++nf) {
                    const int nc = wn * 64 + nf * 16 + lr;       // 0..127
                    const int b16 = nc >> 2;                     // 0..31
#pragma unroll
                    for (int r = 0; r < 4; ++r) {
                        const int ml = mf * 16 + lg * 4 + r;     // 0..63
                        const int sb = (b16 & 24) | ((b16 & 7) ^ (ml & 7));
                        *reinterpret_cast<float*>(smem + ml * 512 + sb * 16 + (nc & 3) * 4)
                            = acc[mf][nf][r];
                    }
                }
            }
        }
        __syncthreads();
#pragma unroll
        for (int it = 0; it < 8; ++it) {
            const int fl = it * 256 + t;       // 0..2047 float4 index
            const int ml = fl >> 5;            // 0..63
            const int b = fl & 31;             // logical 16B block
            const int sb = (b & 24) | ((b & 7) ^ (ml & 7));
            const f32x4 v = *reinterpret_cast<const f32x4*>(smem + ml * 512 + sb * 16);
            __builtin_nontemporal_store(v,
                reinterpret_cast<f32x4*>(ob + (size_t)(m0 + c * 64 + ml) * SEQ + n0 + b * 4));
        }
    }
}

extern "C" void kernel_launch(void* const* d_in, const int* in_sizes, int n_in,
                              void* d_out, int out_size, void* d_ws, size_t ws_size,
                              hipStream_t stream) {
    const float* input = (const float*)d_in[0];
    const float* W     = (const float*)d_in[1];
    const float* bias  = (const float*)d_in[2];
    float* out = (float*)d_out;

    const size_t QK_ELEMS = (size_t)BATCH * NHEAD * SEQ * HSZ;   // 6.29M
    unsigned short* qws = (unsigned short*)d_ws;
    unsigned short* kws = qws + QK_ELEMS;
    unsigned short* Wt  = kws + QK_ELEMS;
    unsigned short* Abf = Wt + (size_t)NDIM * KDIM;
    float2* tab = (float2*)(Abf + (size_t)BATCH * SEQ * KDIM);

    hipLaunchKernelGGL(prep, dim3(NCONV + NTRAN + NTAB), dim3(256), 0, stream,
                       input, W, Abf, Wt, tab);
    hipLaunchKernelGGL(gemm1_rope, dim3(768), dim3(512), 0, stream,
                       Abf, Wt, bias, tab, qws, kws);
    hipLaunchKernelGGL(qk_logits, dim3(96 * 64), dim3(256), 0, stream, qws, kws, out);
}